// Round 6
// baseline (203.560 us; speedup 1.0000x reference)
//
#include <hip/hip_runtime.h>

// MoE: out[b,:] = sum_e softmax(gate(x))[b,e] * (W3_e^T @ relu(W2_e^T @ relu(W1_e^T @ x_b + b1) + b2) + b3)
// Tokens-as-N MFMA. L1 uses 16x16x16 f16 (K=7 useful, k=4q+j). L2/L3/gate-L2 use 16x16x32 f16
// with K-permutation pi(q*8+j)=q*4+(j&3)+16*(j>>2) so C/D layout == next layer's B layout
// in-lane (HW-verified: absmax 0.0156).
// R6: wave-specialization (4 experts/wave, R5) + AGPR-pinned weight fragments (R4's proven
//     spill-killer). The allocator's occupancy heuristic capped arch VGPRs at 64 in R5 and
//     spilled 33 dwords/thread (WRITE 43MB); attributes don't control it (R3/R5 evidence).
//     Pinning the 72 loop-invariant weight regs into the AGPR file leaves ~60 arch regs of
//     temps -> total ~136 unified -> 3 waves/SIMD, zero spills, latency actually hidden.

typedef _Float16 half2_t __attribute__((ext_vector_type(2)));
typedef _Float16 half4_t __attribute__((ext_vector_type(4)));
typedef _Float16 half8_t __attribute__((ext_vector_type(8)));
typedef __fp16   fp16v2  __attribute__((ext_vector_type(2)));
typedef float  float4_t __attribute__((ext_vector_type(4)));
typedef float  float2_t __attribute__((ext_vector_type(2)));
typedef int    int2_t   __attribute__((ext_vector_type(2)));
typedef int    int4_t   __attribute__((ext_vector_type(4)));

#define MFMA_K32(A, B, C) __builtin_amdgcn_mfma_f32_16x16x32_f16((A), (B), (C), 0, 0, 0)
#define MFMA_K16(A, B, C) __builtin_amdgcn_mfma_f32_16x16x16f16((A), (B), (C), 0, 0, 0)

static constexpr int E_ = 8, DIN_ = 6, H_ = 32, EPW_ = 4;   // experts per wave

union H8U { half2_t h2[4]; half8_t h8; int4_t i4; };
union H4U { half2_t h2[2]; half4_t h4; int2_t i2; };
union HI  { half2_t h; int i; };
union PKU { fp16v2 p; half2_t h; };

__device__ __forceinline__ half2_t pkrtz(float a, float b) {
    PKU u; u.p = __builtin_amdgcn_cvt_pkrtz(a, b);
    return u.h;
}

__device__ __forceinline__ half2_t relu2(half2_t v) {
    const half2_t z = {(_Float16)0.0f, (_Float16)0.0f};
    return __builtin_elementwise_max(v, z);
}

__global__ __launch_bounds__(128)
void moe_kernel(
    const float* __restrict__ x,  const float* __restrict__ W1, const float* __restrict__ b1,
    const float* __restrict__ W2, const float* __restrict__ b2, const float* __restrict__ W3,
    const float* __restrict__ b3, const float* __restrict__ Wg1, const float* __restrict__ bg1,
    const float* __restrict__ Wg2, const float* __restrict__ bg2,
    float* __restrict__ out, int nTiles, int tilesPerBlock)
{
    const int tid  = threadIdx.x;
    const int lane = tid & 63;
    const int t    = lane & 15;   // token slot
    const int q    = lane >> 4;   // K-quad
    const int wv   = tid >> 6;    // wave in block: 0 or 1
    const int eb   = wv * EPW_;   // this wave's expert base

    // ---- LDS: b2 bias pairs in pi-order keyed [e][q] (broadcast reads), + cross-wave combine buf
    __shared__ __align__(16) int b2pk[E_ * 4 * 4];       // 512 B
    __shared__ float2_t cbuf[2][16];                     // 256 B, parity double-buffered
    if (tid < E_ * 4 * 4) {                              // 128 entries == blockDim
        int e  = tid >> 4;
        int qq = (tid >> 2) & 3;
        int k  = tid & 3;
        int ch = ((k >> 1) << 4) + qq * 4 + ((k & 1) << 1);   // pi-pair base channel
        HI u; u.h = pkrtz(b2[e * H_ + ch], b2[e * H_ + ch + 1]);
        b2pk[tid] = u.i;
    }
    __syncthreads();

    // ---- gate L1 A-fragments (K=16, k=4q+j; slots 0..5 = x features, 6 = bias-as-1.0)
    H4U G1[2];
    #pragma unroll
    for (int f = 0; f < 2; ++f) {
        H4U u;
        float v0 = 0.f, v1 = 0.f, v2 = 0.f, v3 = 0.f;
        if (q == 0) {
            v0 = Wg1[0 * H_ + f * 16 + t]; v1 = Wg1[1 * H_ + f * 16 + t];
            v2 = Wg1[2 * H_ + f * 16 + t]; v3 = Wg1[3 * H_ + f * 16 + t];
        } else if (q == 1) {
            v0 = Wg1[4 * H_ + f * 16 + t]; v1 = Wg1[5 * H_ + f * 16 + t];
            v2 = bg1[f * 16 + t];          v3 = 0.f;
        }
        u.h2[0] = pkrtz(v0, v1); u.h2[1] = pkrtz(v2, v3);
        G1[f] = u;
    }
    // ---- gate L2 A-fragment (K=32, pi layout)
    H8U G2;
    {
        #pragma unroll
        for (int p = 0; p < 4; ++p) {
            int c0 = ((p >> 1) << 4) + q * 4 + ((p & 1) << 1);
            float v0 = (t < E_) ? Wg2[c0 * E_ + t] : 0.f;
            float v1 = (t < E_) ? Wg2[(c0 + 1) * E_ + t] : 0.f;
            G2.h2[p] = pkrtz(v0, v1);
        }
    }

    // ---- this wave's 4 experts: L1 (K16), L2 (K32 pi), L3 (K32 pi, block-diag rows)
    H4U W1F[EPW_][2];
    H8U W2F[EPW_][2], W3F[EPW_];
    #pragma unroll
    for (int j = 0; j < EPW_; ++j) {
        const int e = eb + j;
        #pragma unroll
        for (int f = 0; f < 2; ++f) {
            H4U u;
            float v0 = 0.f, v1 = 0.f, v2 = 0.f, v3 = 0.f;
            const float* We = W1 + (size_t)e * DIN_ * H_ + f * 16 + t;
            if (q == 0)      { v0 = We[0 * H_]; v1 = We[1 * H_]; v2 = We[2 * H_]; v3 = We[3 * H_]; }
            else if (q == 1) { v0 = We[4 * H_]; v1 = We[5 * H_]; v2 = b1[e * H_ + f * 16 + t]; }
            u.h2[0] = pkrtz(v0, v1); u.h2[1] = pkrtz(v2, v3);
            W1F[j][f] = u;
        }
        #pragma unroll
        for (int f = 0; f < 2; ++f) {
            #pragma unroll
            for (int p = 0; p < 4; ++p) {
                int c0 = ((p >> 1) << 4) + q * 4 + ((p & 1) << 1);
                float v0 = W2[(e * H_ + c0) * H_ + f * 16 + t];
                float v1 = W2[(e * H_ + c0 + 1) * H_ + f * 16 + t];
                W2F[j][f].h2[p] = pkrtz(v0, v1);
            }
        }
        {
            #pragma unroll
            for (int p = 0; p < 4; ++p) {
                int c0 = ((p >> 1) << 4) + q * 4 + ((p & 1) << 1);
                float v0 = 0.f, v1 = 0.f;
                if ((t >> 1) == e) {      // Y rows m=(e',o): this expert's rows only
                    v0 = W3[(e * H_ + c0) * 2 + (t & 1)];
                    v1 = W3[(e * H_ + c0 + 1) * 2 + (t & 1)];
                }
                W3F[j].h2[p] = pkrtz(v0, v1);
            }
        }
    }

    // ---- pin all loop-invariant weight fragments into the AGPR file (72 regs).
    // gfx950 MFMA reads srcA from AGPR directly (ISA §10); arch VGPRs then hold only
    // temps (~60) -> total ~136 unified -> 3 waves/SIMD, no scratch spills (R4 evidence).
    #pragma unroll
    for (int f = 0; f < 2; ++f) asm("" : "+a"(G1[f].i2));
    asm("" : "+a"(G2.i4));
    #pragma unroll
    for (int j = 0; j < EPW_; ++j) {
        asm("" : "+a"(W1F[j][0].i2));
        asm("" : "+a"(W1F[j][1].i2));
        asm("" : "+a"(W2F[j][0].i4));
        asm("" : "+a"(W2F[j][1].i4));
        asm("" : "+a"(W3F[j].i4));
    }

    // ---- persistent C-inits: bg2 for the gate; b3 folded into wave0's Y only (added once)
    float4_t bg2F, b3F;
    #pragma unroll
    for (int r = 0; r < 4; ++r) {
        int m = q * 4 + r;
        bg2F[r] = (m < E_) ? bg2[m] : 0.f;
        b3F[r]  = (wv == 0) ? b3[m] : 0.f;
    }
    const float4_t zero4 = {0.f, 0.f, 0.f, 0.f};

    // bpermute byte address for gate distribution: pull from lane (q>>1)*16 + t
    const int gsrc = ((((q >> 1) << 4) | t) << 2);

    const int tile0 = blockIdx.x * tilesPerBlock;

    const float* xp = x + ((size_t)tile0 * 16 + t) * DIN_;
    float2_t xa = {0.f, 0.f}, xb = {0.f, 0.f}, xc = {0.f, 0.f};
    if (tile0 < nTiles) {
        xa = *(const float2_t*)(xp + 0);
        xb = *(const float2_t*)(xp + 2);
        xc = *(const float2_t*)(xp + 4);
    }

    const half2_t one0  = pkrtz(1.f, 0.f);
    const half2_t zeroh = {(_Float16)0.f, (_Float16)0.f};

    for (int it = 0; it < tilesPerBlock; ++it) {
        const int tile = tile0 + it;
        if (tile >= nTiles) break;          // uniform across the block

        // ---- x B-fragment (K=16): k=4q+j; q0:(x0..x3) q1:(x4,x5,1,0) q2/q3:0
        H4U ux;
        if (q == 0)      { ux.h2[0] = pkrtz(xa[0], xa[1]); ux.h2[1] = pkrtz(xb[0], xb[1]); }
        else if (q == 1) { ux.h2[0] = pkrtz(xc[0], xc[1]); ux.h2[1] = one0; }
        else             { ux.h2[0] = zeroh;               ux.h2[1] = zeroh; }
        const half4_t xB = ux.h4;

        // ---- prefetch next tile's x
        if ((it + 1) < tilesPerBlock && (tile + 1) < nTiles) {
            const float* xn = xp + (size_t)(it + 1) * 16 * DIN_;
            xa = *(const float2_t*)(xn + 0);
            xb = *(const float2_t*)(xn + 2);
            xc = *(const float2_t*)(xn + 4);
        }

        // ---- gate (both waves compute it; avoids cross-wave gate traffic)
        float4_t hgLo = MFMA_K16(G1[0].h4, xB, zero4);
        float4_t hgHi = MFMA_K16(G1[1].h4, xB, zero4);
        H8U uh;
        uh.h2[0] = relu2(pkrtz(hgLo[0], hgLo[1]));
        uh.h2[1] = relu2(pkrtz(hgLo[2], hgLo[3]));
        uh.h2[2] = relu2(pkrtz(hgHi[0], hgHi[1]));
        uh.h2[3] = relu2(pkrtz(hgHi[2], hgHi[3]));
        float4_t gl = MFMA_K32(G2.h8, uh.h8, bg2F);

        // ---- softmax over 8 experts (lanes q=0 hold e0..3, q=1 hold e4..7 for token t)
        float mx = fmaxf(fmaxf(gl[0], gl[1]), fmaxf(gl[2], gl[3]));
        mx = fmaxf(mx, __shfl_xor(mx, 16));
        const float L2E = 1.44269504f;
        float mk = mx * L2E;
        float ex0 = __builtin_amdgcn_exp2f(gl[0] * L2E - mk);
        float ex1 = __builtin_amdgcn_exp2f(gl[1] * L2E - mk);
        float ex2 = __builtin_amdgcn_exp2f(gl[2] * L2E - mk);
        float ex3 = __builtin_amdgcn_exp2f(gl[3] * L2E - mk);
        float s = (ex0 + ex1) + (ex2 + ex3);
        s += __shfl_xor(s, 16);
        float rs = __builtin_amdgcn_rcpf(s);
        HI pa, pb;
        pa.h = pkrtz(ex0 * rs, ex1 * rs);
        pb.h = pkrtz(ex2 * rs, ex3 * rs);
        int va = __builtin_amdgcn_ds_bpermute(gsrc, pa.i);
        int vb = __builtin_amdgcn_ds_bpermute(gsrc, pb.i);
        HI gsel; gsel.i = (q & 1) ? vb : va;       // lane(q,t): g[t,2q], g[t,2q+1]
        float ga = (float)gsel.h[0];
        float gb = (float)gsel.h[1];

        // ---- this wave's 4 experts
        float4_t Y = b3F;
        #pragma unroll
        for (int j = 0; j < EPW_; ++j) {
            float4_t lo = MFMA_K16(W1F[j][0].h4, xB, zero4);
            float4_t hi = MFMA_K16(W1F[j][1].h4, xB, zero4);
            H8U u1;
            u1.h2[0] = relu2(pkrtz(lo[0], lo[1]));
            u1.h2[1] = relu2(pkrtz(lo[2], lo[3]));
            u1.h2[2] = relu2(pkrtz(hi[0], hi[1]));
            u1.h2[3] = relu2(pkrtz(hi[2], hi[3]));
            float4_t lo2 = MFMA_K32(W2F[j][0].h8, u1.h8, zero4);
            float4_t hi2 = MFMA_K32(W2F[j][1].h8, u1.h8, zero4);
            H8U ub; ub.i4 = *(const int4_t*)&b2pk[((eb + j) * 4 + q) * 4];   // broadcast
            H8U u2;
            u2.h2[0] = relu2(pkrtz(lo2[0], lo2[1]) + ub.h2[0]);
            u2.h2[1] = relu2(pkrtz(lo2[2], lo2[3]) + ub.h2[1]);
            u2.h2[2] = relu2(pkrtz(hi2[0], hi2[1]) + ub.h2[2]);
            u2.h2[3] = relu2(pkrtz(hi2[2], hi2[3]) + ub.h2[3]);
            Y = MFMA_K32(W3F[j].h8, u2.h8, Y);
        }

        // ---- gated partial: Y rows m=q*4+r are (e=2q+(r>>1), o=r&1); reduce across quads
        float p0 = ga * Y[0] + gb * Y[2];
        float p1 = ga * Y[1] + gb * Y[3];
        p0 += __shfl_xor(p0, 16);
        p0 += __shfl_xor(p0, 32);
        p1 += __shfl_xor(p1, 16);
        p1 += __shfl_xor(p1, 32);

        // ---- cross-wave combine: parity double-buffer + one barrier per tile
        if (wv == 1 && lane < 16) {
            float2_t o = {p0, p1};
            cbuf[it & 1][t] = o;
        }
        __syncthreads();
        if (wv == 0 && lane < 16) {
            float2_t o = cbuf[it & 1][t];
            o[0] += p0; o[1] += p1;
            *(float2_t*)(out + ((size_t)tile * 16 + t) * 2) = o;
        }
    }
}

extern "C" void kernel_launch(void* const* d_in, const int* in_sizes, int n_in,
                              void* d_out, int out_size, void* d_ws, size_t ws_size,
                              hipStream_t stream) {
    const float* x   = (const float*)d_in[0];
    const float* W1  = (const float*)d_in[1];
    const float* b1  = (const float*)d_in[2];
    const float* W2  = (const float*)d_in[3];
    const float* b2  = (const float*)d_in[4];
    const float* W3  = (const float*)d_in[5];
    const float* b3  = (const float*)d_in[6];
    const float* Wg1 = (const float*)d_in[7];
    const float* bg1 = (const float*)d_in[8];
    const float* Wg2 = (const float*)d_in[9];
    const float* bg2 = (const float*)d_in[10];
    float* out = (float*)d_out;

    const int B      = in_sizes[0] / DIN_;
    const int nTiles = (B + 15) / 16;
    const int blocks = 2048;                      // 65536/2048 = 32 tiles/block exactly
    const int tpb    = (nTiles + blocks - 1) / blocks;

    moe_kernel<<<blocks, 128, 0, stream>>>(x, W1, b1, W2, b2, W3, b3,
                                           Wg1, bg1, Wg2, bg2, out, nTiles, tpb);
}

// Round 7
// 155.589 us; speedup vs baseline: 1.3083x; 1.3083x over previous
//
#include <hip/hip_runtime.h>

// MoE: out[b,:] = sum_e softmax(gate(x))[b,e] * (W3_e^T @ relu(W2_e^T @ relu(W1_e^T @ x_b + b1) + b2) + b3)
// Tokens-as-N MFMA. L1 uses 16x16x16 f16 (K=7 useful, k=4q+j). L2/L3/gate-L2 use 16x16x32 f16
// with K-permutation pi(q*8+j)=q*4+(j&3)+16*(j>>2) so C/D layout == next layer's B layout
// in-lane (HW-verified across R2-R6: absmax 0.0156).
// R7: 2 experts/wave, 4-wave blocks, all waves on one tile. Evidence R2-R6: the allocator
//     targets 2x the declared min-waves (R2 min2->128 regs, R5 min4->64 regs); AGPR ties get
//     copied back per use (R6). So shrink the kernel to ~95 peak regs and declare
//     __launch_bounds__(256,2) -> 128-reg budget, no spills, 4 waves/SIMD. Gate recomputed
//     per wave (cheap); softmax max-sub dropped (logits bounded, log2e pre-folded into Wg2);
//     b2/b3 in regs; single ds_bpermute replaces the quad shfl-reduction.

typedef _Float16 half2_t __attribute__((ext_vector_type(2)));
typedef _Float16 half4_t __attribute__((ext_vector_type(4)));
typedef _Float16 half8_t __attribute__((ext_vector_type(8)));
typedef __fp16   fp16v2  __attribute__((ext_vector_type(2)));
typedef float  float4_t __attribute__((ext_vector_type(4)));
typedef float  float2_t __attribute__((ext_vector_type(2)));
typedef int    int2_t   __attribute__((ext_vector_type(2)));
typedef int    int4_t   __attribute__((ext_vector_type(4)));

#define MFMA_K32(A, B, C) __builtin_amdgcn_mfma_f32_16x16x32_f16((A), (B), (C), 0, 0, 0)
#define MFMA_K16(A, B, C) __builtin_amdgcn_mfma_f32_16x16x16f16((A), (B), (C), 0, 0, 0)

static constexpr int E_ = 8, DIN_ = 6, H_ = 32, EPW_ = 2;   // experts per wave

union H8U { half2_t h2[4]; half8_t h8; int4_t i4; };
union H4U { half2_t h2[2]; half4_t h4; int2_t i2; };
union HI  { half2_t h; int i; };
union PKU { fp16v2 p; half2_t h; };
union FI  { float f; int i; };

__device__ __forceinline__ half2_t pkrtz(float a, float b) {
    PKU u; u.p = __builtin_amdgcn_cvt_pkrtz(a, b);
    return u.h;
}

__device__ __forceinline__ half2_t relu2(half2_t v) {
    const half2_t z = {(_Float16)0.0f, (_Float16)0.0f};
    return __builtin_elementwise_max(v, z);
}

__device__ __forceinline__ float bperm_f(int addr, float v) {
    FI u; u.f = v;
    u.i = __builtin_amdgcn_ds_bpermute(addr, u.i);
    return u.f;
}

__global__ __launch_bounds__(256, 2)
void moe_kernel(
    const float* __restrict__ x,  const float* __restrict__ W1, const float* __restrict__ b1,
    const float* __restrict__ W2, const float* __restrict__ b2, const float* __restrict__ W3,
    const float* __restrict__ b3, const float* __restrict__ Wg1, const float* __restrict__ bg1,
    const float* __restrict__ Wg2, const float* __restrict__ bg2,
    float* __restrict__ out, int nTiles, int tilesPerBlock)
{
    const int tid  = threadIdx.x;
    const int lane = tid & 63;
    const int t    = lane & 15;   // token slot
    const int q    = lane >> 4;   // K-quad
    const int wv   = tid >> 6;    // wave in block: 0..3
    const int eb   = wv * EPW_;   // this wave's expert base (2 experts)

    __shared__ float2_t cbuf[2][4][16];   // parity double-buffered cross-wave partials, 1 KB

    const float L2E = 1.44269504f;

    // ---- gate L1 A-fragments (K=16, k=4q+j; slots 0..5 = x features, 6 = bias-as-1.0)
    H4U G1[2];
    #pragma unroll
    for (int f = 0; f < 2; ++f) {
        float v0 = 0.f, v1 = 0.f, v2 = 0.f, v3 = 0.f;
        if (q == 0) {
            v0 = Wg1[0 * H_ + f * 16 + t]; v1 = Wg1[1 * H_ + f * 16 + t];
            v2 = Wg1[2 * H_ + f * 16 + t]; v3 = Wg1[3 * H_ + f * 16 + t];
        } else if (q == 1) {
            v0 = Wg1[4 * H_ + f * 16 + t]; v1 = Wg1[5 * H_ + f * 16 + t];
            v2 = bg1[f * 16 + t];          v3 = 0.f;
        }
        G1[f].h2[0] = pkrtz(v0, v1); G1[f].h2[1] = pkrtz(v2, v3);
    }
    // ---- gate L2 A-fragment (K=32, pi layout), pre-scaled by log2(e) so logits are exp2-ready
    H8U G2;
    #pragma unroll
    for (int p = 0; p < 4; ++p) {
        int c0 = ((p >> 1) << 4) + q * 4 + ((p & 1) << 1);
        float v0 = (t < E_) ? Wg2[c0 * E_ + t] * L2E : 0.f;
        float v1 = (t < E_) ? Wg2[(c0 + 1) * E_ + t] * L2E : 0.f;
        G2.h2[p] = pkrtz(v0, v1);
    }

    // ---- this wave's 2 experts: L1 (K16), L2 (K32 pi), L3 (K32 pi, block-diag rows), b2 pairs
    H4U W1F[EPW_][2];
    H8U W2F[EPW_][2], W3F[EPW_], B2R[EPW_];
    #pragma unroll
    for (int j = 0; j < EPW_; ++j) {
        const int e = eb + j;
        #pragma unroll
        for (int f = 0; f < 2; ++f) {
            float v0 = 0.f, v1 = 0.f, v2 = 0.f, v3 = 0.f;
            const float* We = W1 + (size_t)e * DIN_ * H_ + f * 16 + t;
            if (q == 0)      { v0 = We[0 * H_]; v1 = We[1 * H_]; v2 = We[2 * H_]; v3 = We[3 * H_]; }
            else if (q == 1) { v0 = We[4 * H_]; v1 = We[5 * H_]; v2 = b1[e * H_ + f * 16 + t]; }
            W1F[j][f].h2[0] = pkrtz(v0, v1); W1F[j][f].h2[1] = pkrtz(v2, v3);
        }
        #pragma unroll
        for (int p = 0; p < 4; ++p) {
            int c0 = ((p >> 1) << 4) + q * 4 + ((p & 1) << 1);
            W2F[j][0].h2[p] = pkrtz(W2[(e * H_ + c0) * H_ + 0  + t], W2[(e * H_ + c0 + 1) * H_ + 0  + t]);
            W2F[j][1].h2[p] = pkrtz(W2[(e * H_ + c0) * H_ + 16 + t], W2[(e * H_ + c0 + 1) * H_ + 16 + t]);
            B2R[j].h2[p]    = pkrtz(b2[e * H_ + c0], b2[e * H_ + c0 + 1]);
            float v0 = 0.f, v1 = 0.f;
            if ((t >> 1) == e) {      // Y rows m=(e',o): this expert's rows only
                v0 = W3[(e * H_ + c0) * 2 + (t & 1)];
                v1 = W3[(e * H_ + c0 + 1) * 2 + (t & 1)];
            }
            W3F[j].h2[p] = pkrtz(v0, v1);
        }
    }

    // ---- persistent C-inits: bg2 (log2-domain) for the gate; b3 per-row (only quad q==wv is
    //      consumed by the bpermute pull, and its rows m=4wv+r are exactly this wave's experts)
    float4_t bg2F, b3F;
    #pragma unroll
    for (int r = 0; r < 4; ++r) {
        int m = q * 4 + r;
        bg2F[r] = (m < E_) ? bg2[m] * L2E : 0.f;
        b3F[r]  = b3[m];
    }
    const float4_t zero4 = {0.f, 0.f, 0.f, 0.f};

    // bpermute byte addrs: gate pull from lane (q>>1)*16+t; combine pull from lane wv*16+t
    const int gsrc = ((((q >> 1) << 4) | t) << 2);
    const int csrc = (((wv << 4) | t) << 2);

    const int tile0 = blockIdx.x * tilesPerBlock;

    const float* xp = x + ((size_t)tile0 * 16 + t) * DIN_;
    float2_t xa = {0.f, 0.f}, xb = {0.f, 0.f}, xc = {0.f, 0.f};
    if (tile0 < nTiles) {
        xa = *(const float2_t*)(xp + 0);
        xb = *(const float2_t*)(xp + 2);
        xc = *(const float2_t*)(xp + 4);
    }

    const half2_t one0  = pkrtz(1.f, 0.f);
    const half2_t zeroh = {(_Float16)0.f, (_Float16)0.f};

    for (int it = 0; it < tilesPerBlock; ++it) {
        const int tile = tile0 + it;
        if (tile >= nTiles) break;          // uniform across the block

        // ---- x B-fragment (K=16): k=4q+j; q0:(x0..x3) q1:(x4,x5,1,0) q2/q3:0
        H4U ux;
        if (q == 0)      { ux.h2[0] = pkrtz(xa[0], xa[1]); ux.h2[1] = pkrtz(xb[0], xb[1]); }
        else if (q == 1) { ux.h2[0] = pkrtz(xc[0], xc[1]); ux.h2[1] = one0; }
        else             { ux.h2[0] = zeroh;               ux.h2[1] = zeroh; }
        const half4_t xB = ux.h4;

        // ---- prefetch next tile's x
        if ((it + 1) < tilesPerBlock && (tile + 1) < nTiles) {
            const float* xn = xp + (size_t)(it + 1) * 16 * DIN_;
            xa = *(const float2_t*)(xn + 0);
            xb = *(const float2_t*)(xn + 2);
            xc = *(const float2_t*)(xn + 4);
        }

        // ---- gate (each wave computes it; logits already in log2 domain)
        float4_t hgLo = MFMA_K16(G1[0].h4, xB, zero4);
        float4_t hgHi = MFMA_K16(G1[1].h4, xB, zero4);
        H8U uh;
        uh.h2[0] = relu2(pkrtz(hgLo[0], hgLo[1]));
        uh.h2[1] = relu2(pkrtz(hgLo[2], hgLo[3]));
        uh.h2[2] = relu2(pkrtz(hgHi[0], hgHi[1]));
        uh.h2[3] = relu2(pkrtz(hgHi[2], hgHi[3]));
        float4_t gl = MFMA_K32(G2.h8, uh.h8, bg2F);

        // ---- softmax over 8 experts, no max-subtraction (|logit| small by construction)
        float ex0 = __builtin_amdgcn_exp2f(gl[0]);
        float ex1 = __builtin_amdgcn_exp2f(gl[1]);
        float ex2 = __builtin_amdgcn_exp2f(gl[2]);
        float ex3 = __builtin_amdgcn_exp2f(gl[3]);
        float s = (ex0 + ex1) + (ex2 + ex3);
        s += __shfl_xor(s, 16);
        float rs = __builtin_amdgcn_rcpf(s);
        HI pa, pb;
        pa.h = pkrtz(ex0 * rs, ex1 * rs);
        pb.h = pkrtz(ex2 * rs, ex3 * rs);
        int va = __builtin_amdgcn_ds_bpermute(gsrc, pa.i);
        int vb = __builtin_amdgcn_ds_bpermute(gsrc, pb.i);
        HI gsel; gsel.i = (q & 1) ? vb : va;       // lane(q,t): g[t,2q], g[t,2q+1]
        float ga = (float)gsel.h[0];
        float gb = (float)gsel.h[1];

        // ---- this wave's 2 experts
        float4_t Y = b3F;
        #pragma unroll
        for (int j = 0; j < EPW_; ++j) {
            float4_t lo = MFMA_K16(W1F[j][0].h4, xB, zero4);
            float4_t hi = MFMA_K16(W1F[j][1].h4, xB, zero4);
            H8U u1;
            u1.h2[0] = relu2(pkrtz(lo[0], lo[1]));
            u1.h2[1] = relu2(pkrtz(lo[2], lo[3]));
            u1.h2[2] = relu2(pkrtz(hi[0], hi[1]));
            u1.h2[3] = relu2(pkrtz(hi[2], hi[3]));
            float4_t lo2 = MFMA_K32(W2F[j][0].h8, u1.h8, zero4);
            float4_t hi2 = MFMA_K32(W2F[j][1].h8, u1.h8, zero4);
            H8U u2;
            u2.h2[0] = relu2(pkrtz(lo2[0], lo2[1]) + B2R[j].h2[0]);
            u2.h2[1] = relu2(pkrtz(lo2[2], lo2[3]) + B2R[j].h2[1]);
            u2.h2[2] = relu2(pkrtz(hi2[0], hi2[1]) + B2R[j].h2[2]);
            u2.h2[3] = relu2(pkrtz(hi2[2], hi2[3]) + B2R[j].h2[3]);
            Y = MFMA_K32(W3F[j].h8, u2.h8, Y);
        }

        // ---- gated partial: only quad q==wv has this wave's expert rows (m=4wv+r); its lanes
        //      hold the complete 2-expert partial incl. b3. Pull it to lanes<16 directly.
        float p0 = ga * Y[0] + gb * Y[2];
        float p1 = ga * Y[1] + gb * Y[3];
        p0 = bperm_f(csrc, p0);
        p1 = bperm_f(csrc, p1);

        // ---- cross-wave combine: parity double-buffer + one barrier per tile
        if (lane < 16) {
            float2_t o = {p0, p1};
            cbuf[it & 1][wv][t] = o;
        }
        __syncthreads();
        if (wv == 0 && lane < 16) {
            float2_t o  = cbuf[it & 1][0][t];
            float2_t o1 = cbuf[it & 1][1][t];
            float2_t o2 = cbuf[it & 1][2][t];
            float2_t o3 = cbuf[it & 1][3][t];
            o[0] += o1[0] + o2[0] + o3[0];
            o[1] += o1[1] + o2[1] + o3[1];
            *(float2_t*)(out + ((size_t)tile * 16 + t) * 2) = o;
        }
    }
}

extern "C" void kernel_launch(void* const* d_in, const int* in_sizes, int n_in,
                              void* d_out, int out_size, void* d_ws, size_t ws_size,
                              hipStream_t stream) {
    const float* x   = (const float*)d_in[0];
    const float* W1  = (const float*)d_in[1];
    const float* b1  = (const float*)d_in[2];
    const float* W2  = (const float*)d_in[3];
    const float* b2  = (const float*)d_in[4];
    const float* W3  = (const float*)d_in[5];
    const float* b3  = (const float*)d_in[6];
    const float* Wg1 = (const float*)d_in[7];
    const float* bg1 = (const float*)d_in[8];
    const float* Wg2 = (const float*)d_in[9];
    const float* bg2 = (const float*)d_in[10];
    float* out = (float*)d_out;

    const int B      = in_sizes[0] / DIN_;
    const int nTiles = (B + 15) / 16;
    const int blocks = 1024;     // 4 waves/block x 1024 = 4096 waves = 4/SIMD, exactly resident
    const int tpb    = (nTiles + blocks - 1) / blocks;

    moe_kernel<<<blocks, 256, 0, stream>>>(x, W1, b1, W2, b2, W3, b3,
                                           Wg1, bg1, Wg2, bg2, out, nTiles, tpb);
}

// Round 8
// 155.316 us; speedup vs baseline: 1.3106x; 1.0018x over previous
//
#include <hip/hip_runtime.h>

// MoE: out[b,:] = sum_e softmax(gate(x))[b,e] * (W3_e^T @ relu(W2_e^T @ relu(W1_e^T @ x_b + b1) + b2) + b3)
// Tokens-as-N MFMA. L1 uses 16x16x16 f16 (K=7 useful, k=4q+j). L2/L3/gate-L2 use 16x16x32 f16
// with K-permutation pi(q*8+j)=q*4+(j&3)+16*(j>>2) so C/D layout == next layer's B layout
// in-lane (HW-verified across R2-R7: absmax 0.0156).
// R8: R7 (2 experts/wave, 4-wave blocks, 60 VGPR, zero spills) + full residency: 2048 blocks
//     = 8 blocks/CU = 32 waves/CU (R7 launched only 4 waves/SIMD; Occ 36%, VALU idle ~half).
//     Micro: xB build branch-free (quads 2-3 of B may hold garbage since all L1 A-frags are
//     zero at k>=8); softmax normalization deferred to the final write (raw-ex bpermute).

typedef _Float16 half2_t __attribute__((ext_vector_type(2)));
typedef _Float16 half4_t __attribute__((ext_vector_type(4)));
typedef _Float16 half8_t __attribute__((ext_vector_type(8)));
typedef __fp16   fp16v2  __attribute__((ext_vector_type(2)));
typedef float  float4_t __attribute__((ext_vector_type(4)));
typedef float  float2_t __attribute__((ext_vector_type(2)));
typedef int    int2_t   __attribute__((ext_vector_type(2)));
typedef int    int4_t   __attribute__((ext_vector_type(4)));

#define MFMA_K32(A, B, C) __builtin_amdgcn_mfma_f32_16x16x32_f16((A), (B), (C), 0, 0, 0)
#define MFMA_K16(A, B, C) __builtin_amdgcn_mfma_f32_16x16x16f16((A), (B), (C), 0, 0, 0)

static constexpr int E_ = 8, DIN_ = 6, H_ = 32, EPW_ = 2;   // experts per wave

union H8U { half2_t h2[4]; half8_t h8; int4_t i4; };
union H4U { half2_t h2[2]; half4_t h4; int2_t i2; };
union HI  { half2_t h; int i; };
union PKU { fp16v2 p; half2_t h; };
union FI  { float f; int i; };

__device__ __forceinline__ half2_t pkrtz(float a, float b) {
    PKU u; u.p = __builtin_amdgcn_cvt_pkrtz(a, b);
    return u.h;
}

__device__ __forceinline__ half2_t relu2(half2_t v) {
    const half2_t z = {(_Float16)0.0f, (_Float16)0.0f};
    return __builtin_elementwise_max(v, z);
}

__device__ __forceinline__ float bperm_f(int addr, float v) {
    FI u; u.f = v;
    u.i = __builtin_amdgcn_ds_bpermute(addr, u.i);
    return u.f;
}

__global__ __launch_bounds__(256, 2)
void moe_kernel(
    const float* __restrict__ x,  const float* __restrict__ W1, const float* __restrict__ b1,
    const float* __restrict__ W2, const float* __restrict__ b2, const float* __restrict__ W3,
    const float* __restrict__ b3, const float* __restrict__ Wg1, const float* __restrict__ bg1,
    const float* __restrict__ Wg2, const float* __restrict__ bg2,
    float* __restrict__ out, int nTiles, int tilesPerBlock)
{
    const int tid  = threadIdx.x;
    const int lane = tid & 63;
    const int t    = lane & 15;   // token slot
    const int q    = lane >> 4;   // K-quad
    const int wv   = tid >> 6;    // wave in block: 0..3
    const int eb   = wv * EPW_;   // this wave's expert base (2 experts)

    __shared__ float2_t cbuf[2][4][16];   // parity double-buffered cross-wave partials, 1 KB

    const float L2E = 1.44269504f;

    // ---- gate L1 A-fragments (K=16, k=4q+j; slots 0..5 = x features, 6 = bias-as-1.0)
    H4U G1[2];
    #pragma unroll
    for (int f = 0; f < 2; ++f) {
        float v0 = 0.f, v1 = 0.f, v2 = 0.f, v3 = 0.f;
        if (q == 0) {
            v0 = Wg1[0 * H_ + f * 16 + t]; v1 = Wg1[1 * H_ + f * 16 + t];
            v2 = Wg1[2 * H_ + f * 16 + t]; v3 = Wg1[3 * H_ + f * 16 + t];
        } else if (q == 1) {
            v0 = Wg1[4 * H_ + f * 16 + t]; v1 = Wg1[5 * H_ + f * 16 + t];
            v2 = bg1[f * 16 + t];          v3 = 0.f;
        }
        G1[f].h2[0] = pkrtz(v0, v1); G1[f].h2[1] = pkrtz(v2, v3);
    }
    // ---- gate L2 A-fragment (K=32, pi layout), pre-scaled by log2(e) so logits are exp2-ready
    H8U G2;
    #pragma unroll
    for (int p = 0; p < 4; ++p) {
        int c0 = ((p >> 1) << 4) + q * 4 + ((p & 1) << 1);
        float v0 = (t < E_) ? Wg2[c0 * E_ + t] * L2E : 0.f;
        float v1 = (t < E_) ? Wg2[(c0 + 1) * E_ + t] * L2E : 0.f;
        G2.h2[p] = pkrtz(v0, v1);
    }

    // ---- this wave's 2 experts: L1 (K16), L2 (K32 pi), L3 (K32 pi, block-diag rows), b2 pairs
    H4U W1F[EPW_][2];
    H8U W2F[EPW_][2], W3F[EPW_], B2R[EPW_];
    #pragma unroll
    for (int j = 0; j < EPW_; ++j) {
        const int e = eb + j;
        #pragma unroll
        for (int f = 0; f < 2; ++f) {
            float v0 = 0.f, v1 = 0.f, v2 = 0.f, v3 = 0.f;
            const float* We = W1 + (size_t)e * DIN_ * H_ + f * 16 + t;
            if (q == 0)      { v0 = We[0 * H_]; v1 = We[1 * H_]; v2 = We[2 * H_]; v3 = We[3 * H_]; }
            else if (q == 1) { v0 = We[4 * H_]; v1 = We[5 * H_]; v2 = b1[e * H_ + f * 16 + t]; }
            W1F[j][f].h2[0] = pkrtz(v0, v1); W1F[j][f].h2[1] = pkrtz(v2, v3);
        }
        #pragma unroll
        for (int p = 0; p < 4; ++p) {
            int c0 = ((p >> 1) << 4) + q * 4 + ((p & 1) << 1);
            W2F[j][0].h2[p] = pkrtz(W2[(e * H_ + c0) * H_ + 0  + t], W2[(e * H_ + c0 + 1) * H_ + 0  + t]);
            W2F[j][1].h2[p] = pkrtz(W2[(e * H_ + c0) * H_ + 16 + t], W2[(e * H_ + c0 + 1) * H_ + 16 + t]);
            B2R[j].h2[p]    = pkrtz(b2[e * H_ + c0], b2[e * H_ + c0 + 1]);
            float v0 = 0.f, v1 = 0.f;
            if ((t >> 1) == e) {      // Y rows m=(e',o): this expert's rows only
                v0 = W3[(e * H_ + c0) * 2 + (t & 1)];
                v1 = W3[(e * H_ + c0 + 1) * 2 + (t & 1)];
            }
            W3F[j].h2[p] = pkrtz(v0, v1);
        }
    }

    // ---- persistent C-inits: bg2 (log2-domain) for the gate; b3 per-row (only quad q==wv is
    //      consumed by the bpermute pull, and its rows m=4wv+r are exactly this wave's experts)
    float4_t bg2F, b3F;
    #pragma unroll
    for (int r = 0; r < 4; ++r) {
        int m = q * 4 + r;
        bg2F[r] = (m < E_) ? bg2[m] * L2E : 0.f;
        b3F[r]  = b3[m];
    }
    const float4_t zero4 = {0.f, 0.f, 0.f, 0.f};

    // bpermute byte addrs: gate pull from lane (q>>1)*16+t; combine pull from lane wv*16+t
    const int gsrc = ((((q >> 1) << 4) | t) << 2);
    const int csrc = (((wv << 4) | t) << 2);

    const int tile0 = blockIdx.x * tilesPerBlock;

    // ---- per-lane x source (loop-invariant): quad0 reads x[t][0..3]; quads>=1 read x[t][4..5]
    //      (quads 2-3 values are never consumed: all L1 A-frags are zero at k>=8)
    const int xo1 = (q == 0) ? 0 : 4;
    const int xo2 = (q == 0) ? 2 : 4;
    const float* xq = x + ((size_t)tile0 * 16 + t) * DIN_;
    float2_t la = {0.f, 0.f}, lb = {0.f, 0.f};
    if (tile0 < nTiles) {
        la = *(const float2_t*)(xq + xo1);
        lb = *(const float2_t*)(xq + xo2);
    }

    HI onei; onei.h = pkrtz(1.f, 0.f);
    const bool isq0 = (q == 0);

    for (int it = 0; it < tilesPerBlock; ++it) {
        const int tile = tile0 + it;
        if (tile >= nTiles) break;          // uniform across the block

        // ---- x B-fragment (K=16): q0:(x0..x3) q1:(x4,x5,1,dc) q2/q3: dc (A=0 there)
        H4U ux;
        ux.h2[0] = pkrtz(la[0], la[1]);
        HI hb; hb.h = pkrtz(lb[0], lb[1]);
        HI se; se.i = isq0 ? hb.i : onei.i;
        ux.h2[1] = se.h;
        const half4_t xB = ux.h4;

        // ---- prefetch next tile's x
        if ((it + 1) < tilesPerBlock && (tile + 1) < nTiles) {
            const float* xn = xq + (size_t)(it + 1) * 16 * DIN_;
            la = *(const float2_t*)(xn + xo1);
            lb = *(const float2_t*)(xn + xo2);
        }

        // ---- gate (each wave computes it; logits already in log2 domain)
        float4_t hgLo = MFMA_K16(G1[0].h4, xB, zero4);
        float4_t hgHi = MFMA_K16(G1[1].h4, xB, zero4);
        H8U uh;
        uh.h2[0] = relu2(pkrtz(hgLo[0], hgLo[1]));
        uh.h2[1] = relu2(pkrtz(hgLo[2], hgLo[3]));
        uh.h2[2] = relu2(pkrtz(hgHi[0], hgHi[1]));
        uh.h2[3] = relu2(pkrtz(hgHi[2], hgHi[3]));
        float4_t gl = MFMA_K32(G2.h8, uh.h8, bg2F);

        // ---- softmax over 8 experts, no max-sub (|logit| bounded), normalization deferred
        float ex0 = __builtin_amdgcn_exp2f(gl[0]);
        float ex1 = __builtin_amdgcn_exp2f(gl[1]);
        float ex2 = __builtin_amdgcn_exp2f(gl[2]);
        float ex3 = __builtin_amdgcn_exp2f(gl[3]);
        float s = (ex0 + ex1) + (ex2 + ex3);
        s += __shfl_xor(s, 16);
        float rs = __builtin_amdgcn_rcpf(s);   // valid in quads 0-1; used only by wave0 lanes<16
        HI pa, pb;
        pa.h = pkrtz(ex0, ex1);
        pb.h = pkrtz(ex2, ex3);
        int va = __builtin_amdgcn_ds_bpermute(gsrc, pa.i);
        int vb = __builtin_amdgcn_ds_bpermute(gsrc, pb.i);
        HI gsel; gsel.i = (q & 1) ? vb : va;       // lane(q,t): ex[t,2q], ex[t,2q+1]
        float ga = (float)gsel.h[0];
        float gb = (float)gsel.h[1];

        // ---- this wave's 2 experts
        float4_t Y = b3F;
        #pragma unroll
        for (int j = 0; j < EPW_; ++j) {
            float4_t lo = MFMA_K16(W1F[j][0].h4, xB, zero4);
            float4_t hi = MFMA_K16(W1F[j][1].h4, xB, zero4);
            H8U u1;
            u1.h2[0] = relu2(pkrtz(lo[0], lo[1]));
            u1.h2[1] = relu2(pkrtz(lo[2], lo[3]));
            u1.h2[2] = relu2(pkrtz(hi[0], hi[1]));
            u1.h2[3] = relu2(pkrtz(hi[2], hi[3]));
            float4_t lo2 = MFMA_K32(W2F[j][0].h8, u1.h8, zero4);
            float4_t hi2 = MFMA_K32(W2F[j][1].h8, u1.h8, zero4);
            H8U u2;
            u2.h2[0] = relu2(pkrtz(lo2[0], lo2[1]) + B2R[j].h2[0]);
            u2.h2[1] = relu2(pkrtz(lo2[2], lo2[3]) + B2R[j].h2[1]);
            u2.h2[2] = relu2(pkrtz(hi2[0], hi2[1]) + B2R[j].h2[2]);
            u2.h2[3] = relu2(pkrtz(hi2[2], hi2[3]) + B2R[j].h2[3]);
            Y = MFMA_K32(W3F[j].h8, u2.h8, Y);
        }

        // ---- gated partial (ex-weighted, unnormalized): only quad q==wv has this wave's
        //      expert rows (m=4wv+r). Pull it to lanes<16 directly.
        float p0 = ga * Y[0] + gb * Y[2];
        float p1 = ga * Y[1] + gb * Y[3];
        p0 = bperm_f(csrc, p0);
        p1 = bperm_f(csrc, p1);

        // ---- cross-wave combine: parity double-buffer + one barrier per tile; x rs at the end
        if (lane < 16) {
            float2_t o = {p0, p1};
            cbuf[it & 1][wv][t] = o;
        }
        __syncthreads();
        if (wv == 0 && lane < 16) {
            float2_t o  = cbuf[it & 1][0][t];
            float2_t o1 = cbuf[it & 1][1][t];
            float2_t o2 = cbuf[it & 1][2][t];
            float2_t o3 = cbuf[it & 1][3][t];
            o[0] = (o[0] + o1[0] + o2[0] + o3[0]) * rs;
            o[1] = (o[1] + o1[1] + o2[1] + o3[1]) * rs;
            *(float2_t*)(out + ((size_t)tile * 16 + t) * 2) = o;
        }
    }
}

extern "C" void kernel_launch(void* const* d_in, const int* in_sizes, int n_in,
                              void* d_out, int out_size, void* d_ws, size_t ws_size,
                              hipStream_t stream) {
    const float* x   = (const float*)d_in[0];
    const float* W1  = (const float*)d_in[1];
    const float* b1  = (const float*)d_in[2];
    const float* W2  = (const float*)d_in[3];
    const float* b2  = (const float*)d_in[4];
    const float* W3  = (const float*)d_in[5];
    const float* b3  = (const float*)d_in[6];
    const float* Wg1 = (const float*)d_in[7];
    const float* bg1 = (const float*)d_in[8];
    const float* Wg2 = (const float*)d_in[9];
    const float* bg2 = (const float*)d_in[10];
    float* out = (float*)d_out;

    const int B      = in_sizes[0] / DIN_;
    const int nTiles = (B + 15) / 16;
    const int blocks = 2048;     // 8 blocks/CU x 4 waves = 32 waves/CU: full residency at 60 VGPR
    const int tpb    = (nTiles + blocks - 1) / blocks;

    moe_kernel<<<blocks, 256, 0, stream>>>(x, W1, b1, W2, b2, W3, b3,
                                           Wg1, bg1, Wg2, bg2, out, nTiles, tpb);
}